// Round 22
// baseline (288.607 us; speedup 1.0000x reference)
//
#include <hip/hip_runtime.h>
#include <hip/hip_bf16.h>

typedef __attribute__((ext_vector_type(8))) __bf16 bf16x8;
typedef __attribute__((ext_vector_type(4))) float f32x4;

#define DEVI static __device__ __forceinline__

// ---- helpers ---------------------------------------------------------------

DEVI ushort f2bf(float f) {
  unsigned u = __builtin_bit_cast(unsigned, f);
  return (ushort)((u + 0x7fffu + ((u >> 16) & 1u)) >> 16);
}

union BF8 { unsigned u[4]; bf16x8 v; };

DEVI bf16x8 cvt8(const float* __restrict__ p) {
  const f32x4 a = *(const f32x4*)p;
  const f32x4 b = *(const f32x4*)(p + 4);
  BF8 r;
  asm("v_cvt_pk_bf16_f32 %0, %1, %2" : "=v"(r.u[0]) : "v"(a.x), "v"(a.y));
  asm("v_cvt_pk_bf16_f32 %0, %1, %2" : "=v"(r.u[1]) : "v"(a.z), "v"(a.w));
  asm("v_cvt_pk_bf16_f32 %0, %1, %2" : "=v"(r.u[2]) : "v"(b.x), "v"(b.y));
  asm("v_cvt_pk_bf16_f32 %0, %1, %2" : "=v"(r.u[3]) : "v"(b.z), "v"(b.w));
  return r.v;
}

DEVI bf16x8 cvt8r(f32x4 a, f32x4 b) {
  BF8 r;
  asm("v_cvt_pk_bf16_f32 %0, %1, %2" : "=v"(r.u[0]) : "v"(a.x), "v"(a.y));
  asm("v_cvt_pk_bf16_f32 %0, %1, %2" : "=v"(r.u[1]) : "v"(a.z), "v"(a.w));
  asm("v_cvt_pk_bf16_f32 %0, %1, %2" : "=v"(r.u[2]) : "v"(b.x), "v"(b.y));
  asm("v_cvt_pk_bf16_f32 %0, %1, %2" : "=v"(r.u[3]) : "v"(b.z), "v"(b.w));
  return r.v;
}

DEVI unsigned cvtpk1(float lo, float hi) {
  unsigned r;
  asm("v_cvt_pk_bf16_f32 %0, %1, %2" : "=v"(r) : "v"(lo), "v"(hi));
  return r;
}

DEVI void gload16(const void* g, void* l) {
  __builtin_amdgcn_global_load_lds(
      (const __attribute__((address_space(1))) unsigned*)g,
      (__attribute__((address_space(3))) unsigned*)l, 16, 0, 0);
}

DEVI int xcd_swizzle(int bid, int nwg) {
  return (bid & 7) * (nwg >> 3) + (bid >> 3);
}

DEVI f32x4 mfma16(bf16x8 a, bf16x8 b, f32x4 c) {
  return __builtin_amdgcn_mfma_f32_16x16x32_bf16(a, b, c, 0, 0, 0);
}

// ---- converts --------------------------------------------------------------
// cvt_qkv: 8 chunks/thread, all 16 f32x4 NT loads issued back-to-back (dead
// f32 source), then cvt + regular stores (bf16 output re-read by GEMMs).

__global__ __launch_bounds__(256) void cvt_qkv(
    const float* __restrict__ q, const float* __restrict__ k,
    const float* __restrict__ v, ushort* __restrict__ oq,
    ushort* __restrict__ ok2, ushort* __restrict__ ov) {
  const int s = blockIdx.x >> 10;
  const int tb = blockIdx.x & 1023;
  const float* src = s == 0 ? q : (s == 1 ? k : v);
  ushort* dst = s == 0 ? oq : (s == 1 ? ok2 : ov);
  const size_t base = (size_t)tb * 2048 + threadIdx.x;

  f32x4 va[8], vb[8];
#pragma unroll
  for (int j = 0; j < 8; ++j) {
    const float* p = src + (base + j * 256) * 8;
    va[j] = __builtin_nontemporal_load((const f32x4*)p);
    vb[j] = __builtin_nontemporal_load((const f32x4*)(p + 4));
  }
#pragma unroll
  for (int j = 0; j < 8; ++j)
    *(bf16x8*)(dst + (base + j * 256) * 8) = cvt8r(va[j], vb[j]);
}

__global__ __launch_bounds__(256) void cvt_w(
    const float* __restrict__ wq, const float* __restrict__ wk,
    const float* __restrict__ wv, const float* __restrict__ wo,
    ushort* __restrict__ oq, ushort* __restrict__ ok2,
    ushort* __restrict__ ov, ushort* __restrict__ oo) {
  const int s = blockIdx.x >> 7;
  const int tb = blockIdx.x & 127;
  const float* src = s == 0 ? wq : (s == 1 ? wk : (s == 2 ? wv : wo));
  ushort* dst = s == 0 ? oq : (s == 1 ? ok2 : (s == 2 ? ov : oo));
  const unsigned G = 128 * 256;
  const unsigned t = tb * 256 + threadIdx.x;
#pragma unroll
  for (int j = 0; j < 4; ++j) {
    const size_t i = (size_t)t + (size_t)j * G;
    *(bf16x8*)(dst + i * 8) = cvt8(src + i * 8);
  }
}

// ---- GEMM (bf16 A): 256x256 tile, BK=32, 512 threads, fine-phase -----------
// (verified round 17: ~42 us/dispatch at this shape)
// OUT: 0 = f32, 1 = bf16, 2 = bf16 transposed (C^T[col][row], stride 16384)

template <int OUT>
__global__ __launch_bounds__(512, 2) void gemm_8ph(
    const ushort* __restrict__ A, const ushort* __restrict__ B,
    const float* __restrict__ bias, void* __restrict__ Cp, int N, int K) {
  __shared__ __align__(16) ushort Asm[4][8192];
  __shared__ __align__(16) ushort Bsm[4][8192];
  const int tid = threadIdx.x, lane = tid & 63;
  const int wv = tid >> 6;
  const int wr = wv >> 2, wc = wv & 3;
  const int cc = lane & 15, cr = lane >> 4;
  const int nw = N >> 8;
  const int work = xcd_swizzle(blockIdx.x, gridDim.x);
  const size_t m0 = (size_t)(work / nw) * 256;
  const size_t n0 = (size_t)(work % nw) * 256;

  const ushort *ag[2], *bg[2];
#pragma unroll
  for (int h = 0; h < 2; ++h) {
    const int u = tid + h * 512;
    const int row = u >> 2, slot = u & 3;
    const int gc = (slot ^ ((row >> 1) & 3)) * 8;
    ag[h] = A + (m0 + row) * (size_t)K + gc;
    bg[h] = B + (n0 + row) * (size_t)K + gc;
  }

  auto stageh = [&](int buf, int kt, int h) {
    gload16(ag[h] + kt, &Asm[buf][(tid + h * 512) * 8]);
    gload16(bg[h] + kt, &Bsm[buf][(tid + h * 512) * 8]);
  };

  f32x4 acc[8][4] = {};
  const int nt = K >> 5;

  int aoff[8], boff[4];
#pragma unroll
  for (int m = 0; m < 8; ++m) {
    const int row = wr * 128 + m * 16 + cc;
    aoff[m] = (row * 4 + (cr ^ ((row >> 1) & 3))) * 8;
  }
#pragma unroll
  for (int n = 0; n < 4; ++n) {
    const int row = wc * 64 + n * 16 + cc;
    boff[n] = (row * 4 + (cr ^ ((row >> 1) & 3))) * 8;
  }

#pragma unroll
  for (int p = 0; p < 3; ++p) {
    stageh(p, p << 5, 0);
    stageh(p, p << 5, 1);
  }
  asm volatile("s_waitcnt vmcnt(8)" ::: "memory");
  __builtin_amdgcn_s_barrier();
  asm volatile("" ::: "memory");

  for (int k = 0; k < nt; ++k) {
    const ushort* Ab = Asm[k & 3];
    const ushort* Bb = Bsm[k & 3];
    const int wb = (k + 3) & 3;
    const bool more = (k + 3 < nt);
    bf16x8 bf[4], af[4];

#pragma unroll
    for (int n = 0; n < 4; ++n) bf[n] = *(const bf16x8*)&Bb[boff[n]];
#pragma unroll
    for (int m = 0; m < 4; ++m) af[m] = *(const bf16x8*)&Ab[aoff[m]];
    if (more) stageh(wb, (k + 3) << 5, 0);
    __builtin_amdgcn_s_barrier();
    asm volatile("s_waitcnt lgkmcnt(0)" ::: "memory");
    __builtin_amdgcn_s_setprio(1);
#pragma unroll
    for (int m = 0; m < 4; ++m)
#pragma unroll
      for (int n = 0; n < 4; ++n)
        acc[m][n] = mfma16(af[m], bf[n], acc[m][n]);
    __builtin_amdgcn_s_setprio(0);
    asm volatile("" ::: "memory");
    __builtin_amdgcn_s_barrier();

#pragma unroll
    for (int m = 0; m < 4; ++m) af[m] = *(const bf16x8*)&Ab[aoff[4 + m]];
    if (more) stageh(wb, (k + 3) << 5, 1);
    if (k < nt - 3) {
      asm volatile("s_waitcnt vmcnt(8)" ::: "memory");
    } else if (k == nt - 3) {
      asm volatile("s_waitcnt vmcnt(4)" ::: "memory");
    } else if (k == nt - 2) {
      asm volatile("s_waitcnt vmcnt(0)" ::: "memory");
    }
    __builtin_amdgcn_s_barrier();
    asm volatile("s_waitcnt lgkmcnt(0)" ::: "memory");
    __builtin_amdgcn_s_setprio(1);
#pragma unroll
    for (int m = 0; m < 4; ++m)
#pragma unroll
      for (int n = 0; n < 4; ++n)
        acc[4 + m][n] = mfma16(af[m], bf[n], acc[4 + m][n]);
    __builtin_amdgcn_s_setprio(0);
    asm volatile("" ::: "memory");
    __builtin_amdgcn_s_barrier();
  }

#pragma unroll
  for (int n = 0; n < 4; ++n) {
    const size_t col = n0 + wc * 64 + n * 16 + cc;
    const float bval = bias[col];
#pragma unroll
    for (int m = 0; m < 8; ++m) {
      const size_t row0 = m0 + wr * 128 + m * 16 + cr * 4;
#pragma unroll
      for (int r = 0; r < 4; ++r) {
        const float val = acc[m][n][r] + bval;
        if constexpr (OUT == 0)
          ((float*)Cp)[(row0 + r) * N + col] = val;
        else if constexpr (OUT == 1)
          ((ushort*)Cp)[(row0 + r) * N + col] = f2bf(val);
        else
          ((ushort*)Cp)[col * 16384 + row0 + r] = f2bf(val);
      }
    }
  }
}

// ---- windowed attention (round-19 version: q-hoist + cvt_pk + setprio) -----

__global__ __launch_bounds__(512) void attn_kernel(
    const ushort* __restrict__ q, const ushort* __restrict__ k,
    const ushort* __restrict__ vt, ushort* __restrict__ x) {
  __shared__ __align__(16) ushort Ks[256 * 64];
  __shared__ __align__(16) ushort Vt[64 * 256];
  __shared__ ushort Pw[8][16 * 264];
  const int bid = blockIdx.x;
  const int w = bid & 15, h = (bid >> 4) & 15, b = bid >> 8;
  const int tid = threadIdx.x, lane = tid & 63, wv = tid >> 6;
  const int cc = lane & 15, cr = lane >> 4;
  const size_t base = ((size_t)b * 4096 + (size_t)w * 256) * 1024 + h * 64;
  const size_t vbase = ((size_t)h * 64) * 16384 + (size_t)b * 4096 + w * 256;

  const ushort* qp0 = q + base + (size_t)(wv * 32 + cc) * 1024 + cr * 8;
  const ushort* qp1 = q + base + (size_t)(wv * 32 + 16 + cc) * 1024 + cr * 8;
  const bf16x8 qA0 = *(const bf16x8*)qp0;
  const bf16x8 qA1 = *(const bf16x8*)(qp0 + 32);
  const bf16x8 qB0 = *(const bf16x8*)qp1;
  const bf16x8 qB1 = *(const bf16x8*)(qp1 + 32);

#pragma unroll
  for (int i = 0; i < 4; ++i) {
    const int u = tid + i * 512;
    const int row = u >> 3, slot = u & 7;
    gload16(k + base + (size_t)row * 1024 + ((slot ^ (row & 7)) << 3),
            &Ks[u * 8]);
  }
#pragma unroll
  for (int i = 0; i < 4; ++i) {
    const int u = tid + i * 512;
    const int dk = u >> 5, slot = u & 31;
    gload16(vt + vbase + (size_t)dk * 16384 + (((slot & 24) | ((slot ^ dk) & 7)) << 3),
            &Vt[u * 8]);
  }
  __syncthreads();

  ushort* Pp = Pw[wv];
  for (int c = 0; c < 2; ++c) {
    const int qrow0 = wv * 32 + c * 16;
    const bf16x8 qf0 = c == 0 ? qA0 : qB0;
    const bf16x8 qf1 = c == 0 ? qA1 : qB1;

    f32x4 sc[16];
    __builtin_amdgcn_s_setprio(1);
#pragma unroll
    for (int cb = 0; cb < 16; ++cb) {
      const int row = cb * 16 + cc;
      const bf16x8 kb0 = *(const bf16x8*)&Ks[row * 64 + ((cr ^ (row & 7)) << 3)];
      const bf16x8 kb1 =
          *(const bf16x8*)&Ks[row * 64 + (((4 + cr) ^ (row & 7)) << 3)];
      f32x4 z = {0.f, 0.f, 0.f, 0.f};
      z = mfma16(qf0, kb0, z);
      z = mfma16(qf1, kb1, z);
      sc[cb] = z;
    }
    __builtin_amdgcn_s_setprio(0);

    float inv[4];
#pragma unroll
    for (int r = 0; r < 4; ++r) {
      float mx = -1e30f;
#pragma unroll
      for (int cb = 0; cb < 16; ++cb) mx = fmaxf(mx, sc[cb][r]);
      mx = fmaxf(mx, __shfl_xor(mx, 1));
      mx = fmaxf(mx, __shfl_xor(mx, 2));
      mx = fmaxf(mx, __shfl_xor(mx, 4));
      mx = fmaxf(mx, __shfl_xor(mx, 8));
      float sum = 0.f;
#pragma unroll
      for (int cb = 0; cb < 16; ++cb) {
        const float p = __expf((sc[cb][r] - mx) * 0.125f);
        sc[cb][r] = p;
        sum += p;
      }
      sum += __shfl_xor(sum, 1);
      sum += __shfl_xor(sum, 2);
      sum += __shfl_xor(sum, 4);
      sum += __shfl_xor(sum, 8);
      inv[r] = 1.f / sum;
    }

#pragma unroll
    for (int r = 0; r < 4; ++r) {
      ushort* prow = &Pp[(cr * 4 + r) * 264 + cc];
#pragma unroll
      for (int cb = 0; cb < 16; cb += 2) {
        const unsigned pk = cvtpk1(sc[cb][r], sc[cb + 1][r]);
        prow[cb * 16] = (ushort)pk;
        prow[(cb + 1) * 16] = (ushort)(pk >> 16);
      }
    }

    bf16x8 pf[8];
#pragma unroll
    for (int ks = 0; ks < 8; ++ks)
      pf[ks] = *(const bf16x8*)&Pp[cc * 264 + ks * 32 + cr * 8];
    f32x4 o[4] = {};
    __builtin_amdgcn_s_setprio(1);
#pragma unroll
    for (int db = 0; db < 4; ++db) {
      const int row = db * 16 + cc;
#pragma unroll
      for (int ks = 0; ks < 8; ++ks) {
        const int gu = ks * 4 + cr;
        const int lu = (gu & 24) | ((gu ^ row) & 7);
        const bf16x8 bv = *(const bf16x8*)&Vt[row * 256 + lu * 8];
        o[db] = mfma16(pf[ks], bv, o[db]);
      }
    }
    __builtin_amdgcn_s_setprio(0);

#pragma unroll
    for (int db = 0; db < 4; ++db)
#pragma unroll
      for (int r = 0; r < 4; ++r) {
        const int qr = qrow0 + cr * 4 + r;
        x[base + (size_t)qr * 1024 + db * 16 + cc] = f2bf(o[db][r] * inv[r]);
      }
  }
}

// ---- launch ----------------------------------------------------------------

extern "C" void kernel_launch(void* const* d_in, const int* in_sizes, int n_in,
                              void* d_out, int out_size, void* d_ws, size_t ws_size,
                              hipStream_t stream) {
  const float* query = (const float*)d_in[0];
  const float* key_  = (const float*)d_in[1];
  const float* value = (const float*)d_in[2];
  const float* Wq = (const float*)d_in[3];
  const float* bq = (const float*)d_in[4];
  const float* Wk = (const float*)d_in[5];
  const float* bk = (const float*)d_in[6];
  const float* Wv = (const float*)d_in[7];
  const float* bv = (const float*)d_in[8];
  const float* Wo = (const float*)d_in[9];
  const float* bo = (const float*)d_in[10];
  float* out = (float*)d_out;

  // ws: qb/kb/vb bf16 inputs (100 MB) + 4 weights (8 MB) + qp/kp/vtp (100 MB)
  const size_t MN = (size_t)16384 * 1024;
  const size_t WN = (size_t)1024 * 1024;
  ushort* qb = (ushort*)d_ws;
  ushort* kb = qb + MN;
  ushort* vb = kb + MN;
  ushort* wqb = vb + MN;
  ushort* wkb = wqb + WN;
  ushort* wvb = wkb + WN;
  ushort* wob = wvb + WN;
  ushort* qp = wob + WN;
  ushort* kp = qp + MN;
  ushort* vtp = kp + MN;   // V^T [1024][16384]

  const dim3 b256(256), b512(512);
  const dim3 ggrid(256);

  cvt_qkv<<<dim3(3 * 1024), b256, 0, stream>>>(query, key_, value, qb, kb, vb);
  cvt_w<<<dim3(4 * 128), b256, 0, stream>>>(Wq, Wk, Wv, Wo, wqb, wkb, wvb, wob);

  gemm_8ph<1><<<ggrid, b512, 0, stream>>>(qb, wqb, bq, qp, 1024, 1024);
  gemm_8ph<1><<<ggrid, b512, 0, stream>>>(kb, wkb, bk, kp, 1024, 1024);
  gemm_8ph<2><<<ggrid, b512, 0, stream>>>(vb, wvb, bv, vtp, 1024, 1024);

  attn_kernel<<<dim3(1024), b512, 0, stream>>>(qp, kp, vtp, qp /*in-place*/);

  gemm_8ph<0><<<ggrid, b512, 0, stream>>>(qp, wob, bo, out, 1024, 1024);
}